// Round 7
// baseline (165.606 us; speedup 1.0000x reference)
//
#include <hip/hip_runtime.h>

// GBDT ensemble inference — R7: R6 with nt-builtin fix (native vector type).
// Non-temporal x/out streams (keep the 1.6MB hot table L2-resident) + odd LDS
// stride (kill correlated bank pileups). B=32768, T=512, D=8, F=512, C=1.
//
// Mapping (from R5): lane = batch row (64 rows/block), one tree per gather
// instruction; wave owns 32 trees, 4 interleaved chains; leaves accumulate in
// registers -> float4 nt store.

#define BB 32768
#define TT 512
#define FF 512
#define PADW 65536        // T * 2^(D-1)
#define NLV 7             // internal levels below root
#define ROWS 64           // batch rows per block (= lanes per wave)
#define THREADS 1024      // 16 waves
#define WAVES 16
#define TPW 32            // trees per wave = 512/16
#define XSS 515           // odd stride: bank-stride 3 (gcd(3,32)=1) ->
                          // lanes sharing a feature spread over 32 banks

typedef float f32x4 __attribute__((ext_vector_type(4)));

__global__ __launch_bounds__(256) void pack_tables_kernel(
    const int* __restrict__ nodes_lv, const float* __restrict__ biases_lv,
    int2* __restrict__ packed, int n)
{
    int i = blockIdx.x * 256 + threadIdx.x;
    if (i < n) packed[i] = make_int2(nodes_lv[i], __float_as_int(biases_lv[i]));
}

template<bool PACKED>
__global__ __launch_bounds__(THREADS) void gbdt_walk_kernel(
    const float* __restrict__ x,
    const int*   __restrict__ root_nodes,
    const float* __restrict__ root_biases,
    const int*   __restrict__ tree_indices,
    const int*   __restrict__ nodes_lv,
    const float* __restrict__ biases_lv,
    const float* __restrict__ leaf_nodes,
    const int2*  __restrict__ packed,
    float*       __restrict__ out)
{
    __shared__ float xs[ROWS * XSS];        // 131,840 B

    const int tid = threadIdx.x;
    const int b0  = blockIdx.x * ROWS;

    // ---- stage 64 x-rows into LDS: nt global float4 loads,
    //      scalar ds_writes (XSS odd -> float4 LDS writes would misalign) ----
    const f32x4* __restrict__ xr = (const f32x4*)(x + (size_t)b0 * FF);
    #pragma unroll
    for (int i = 0; i < (ROWS * FF / 4) / THREADS; ++i) {   // 8 iters
        int fidx = i * THREADS + tid;       // float4 index over [ROWS][FF/4]
        int r = fidx >> 7, c4 = fidx & 127;
        f32x4 v = __builtin_nontemporal_load(&xr[fidx]);
        float* d = &xs[r * XSS + (c4 << 2)];
        d[0] = v.x; d[1] = v.y; d[2] = v.z; d[3] = v.w;
    }
    __syncthreads();

    // ---- walk: lane = row; wave walks its 32 trees, 4 chains/step ----
    const int wv   = tid >> 6;              // wave 0..15
    const int lane = tid & 63;              // row 0..63
    const int tb   = wv * TPW;
    const float* __restrict__ xrow = &xs[lane * XSS];
    float* __restrict__ orow = out + (size_t)(b0 + lane) * TT;

    #pragma unroll
    for (int s = 0; s < TPW / 4; ++s) {     // 8 steps, 4 interleaved chains
        // wave-uniform tree ids -> scalar loads for root tables
        const int t0 = __builtin_amdgcn_readfirstlane(tb + 4 * s);
        int p0 = tree_indices[t0+0] + (xrow[root_nodes[t0+0]] >= root_biases[t0+0] ? 1 : 0);
        int p1 = tree_indices[t0+1] + (xrow[root_nodes[t0+1]] >= root_biases[t0+1] ? 1 : 0);
        int p2 = tree_indices[t0+2] + (xrow[root_nodes[t0+2]] >= root_biases[t0+2] ? 1 : 0);
        int p3 = tree_indices[t0+3] + (xrow[root_nodes[t0+3]] >= root_biases[t0+3] ? 1 : 0);
        #pragma unroll
        for (int l = 0; l < NLV; ++l) {
            if constexpr (PACKED) {
                const int2 n0 = packed[l * PADW + p0];
                const int2 n1 = packed[l * PADW + p1];
                const int2 n2 = packed[l * PADW + p2];
                const int2 n3 = packed[l * PADW + p3];
                p0 = 2 * p0 + (xrow[n0.x] >= __int_as_float(n0.y) ? 1 : 0);
                p1 = 2 * p1 + (xrow[n1.x] >= __int_as_float(n1.y) ? 1 : 0);
                p2 = 2 * p2 + (xrow[n2.x] >= __int_as_float(n2.y) ? 1 : 0);
                p3 = 2 * p3 + (xrow[n3.x] >= __int_as_float(n3.y) ? 1 : 0);
            } else {
                const int   f0 = nodes_lv[l * PADW + p0];
                const int   f1 = nodes_lv[l * PADW + p1];
                const int   f2 = nodes_lv[l * PADW + p2];
                const int   f3 = nodes_lv[l * PADW + p3];
                const float h0 = biases_lv[l * PADW + p0];
                const float h1 = biases_lv[l * PADW + p1];
                const float h2 = biases_lv[l * PADW + p2];
                const float h3 = biases_lv[l * PADW + p3];
                p0 = 2 * p0 + (xrow[f0] >= h0 ? 1 : 0);
                p1 = 2 * p1 + (xrow[f1] >= h1 ? 1 : 0);
                p2 = 2 * p2 + (xrow[f2] >= h2 ? 1 : 0);
                p3 = 2 * p3 + (xrow[f3] >= h3 ? 1 : 0);
            }
        }
        // leaves for 4 consecutive trees live in this lane -> nt float4 store
        f32x4 v;
        v.x = leaf_nodes[p0];
        v.y = leaf_nodes[p1];
        v.z = leaf_nodes[p2];
        v.w = leaf_nodes[p3];
        __builtin_nontemporal_store(v, (f32x4*)&orow[t0]);
    }
}

extern "C" void kernel_launch(void* const* d_in, const int* in_sizes, int n_in,
                              void* d_out, int out_size, void* d_ws, size_t ws_size,
                              hipStream_t stream) {
    const float* x            = (const float*)d_in[0];
    const int*   root_nodes   = (const int*)  d_in[1];
    const float* root_biases  = (const float*)d_in[2];
    const int*   tree_indices = (const int*)  d_in[3];
    const int*   nodes_lv     = (const int*)  d_in[4];
    const float* biases_lv    = (const float*)d_in[5];
    const float* leaf_nodes   = (const float*)d_in[6];
    float*       out          = (float*)d_out;

    const int n_nodes = NLV * PADW;                     // 458,752
    const size_t packed_bytes = (size_t)n_nodes * 8;    // 3.67 MB

    dim3 grid(BB / ROWS);   // 512 blocks
    dim3 block(THREADS);

    if (ws_size >= packed_bytes) {
        int2* packed = (int2*)d_ws;
        pack_tables_kernel<<<(n_nodes + 255) / 256, 256, 0, stream>>>(
            nodes_lv, biases_lv, packed, n_nodes);
        gbdt_walk_kernel<true><<<grid, block, 0, stream>>>(
            x, root_nodes, root_biases, tree_indices,
            nodes_lv, biases_lv, leaf_nodes, packed, out);
    } else {
        gbdt_walk_kernel<false><<<grid, block, 0, stream>>>(
            x, root_nodes, root_biases, tree_indices,
            nodes_lv, biases_lv, leaf_nodes, (const int2*)nullptr, out);
    }
}

// Round 8
// 74.911 us; speedup vs baseline: 2.2107x; 2.2107x over previous
//
#include <hip/hip_runtime.h>

// GBDT ensemble inference — R8: fused 2-level records (16B, one dwordx4 per
// 2 tree levels) + level6+leaf fused record. VMEM gathers per walk: 8 -> 4.
// B=32768, T=512, D=8, F=512, C=1.
//
// ws layout (int4 records):
//   PT0 [0,1024):      levels 0,1   idx p0 in [0,2T)
//   PT1 [1024,5120):   levels 2,3   idx p2 in [0,8T)
//   PT2 [5120,21504):  levels 4,5   idx p4 in [0,32T)
//   PT3 [21504,87040): level 6+leaf idx p6 in [0,128T)
// Pair rec: {f0|fL<<10|fR<<20, b0, bL, bR}; PT3 rec: {f6, b6, leafL, leafR}.
//
// Mapping (R5): lane = batch row (64 rows/block), wave owns 32 trees,
// 4 interleaved chains/step; leaves -> float4 store. Regular (non-nt) mem ops.

#define BB 32768
#define TT 512
#define FF 512
#define PADW 65536
#define ROWS 64
#define THREADS 1024
#define WAVES 16
#define TPW 32
#define XSS 515           // odd stride: lanes sharing a feature spread banks

#define PT0_OFF 0
#define PT1_OFF 1024
#define PT2_OFF 5120
#define PT3_OFF 21504
#define N_REC   87040     // total int4 records (1.36 MB)

__global__ __launch_bounds__(256) void build_tables_kernel(
    const int*   __restrict__ nodes_lv,
    const float* __restrict__ biases_lv,
    const float* __restrict__ leaf_nodes,
    int4*        __restrict__ ws16)
{
    const int i = blockIdx.x * 256 + threadIdx.x;
    if (i >= N_REC) return;

    int l, p, off;
    if (i < PT1_OFF)      { l = 0; off = PT0_OFF; }
    else if (i < PT2_OFF) { l = 2; off = PT1_OFF; }
    else if (i < PT3_OFF) { l = 4; off = PT2_OFF; }
    else {
        // PT3: level 6 + both leaves
        p = i - PT3_OFF;
        const int   f = nodes_lv[6 * PADW + p];
        const float b = biases_lv[6 * PADW + p];
        const float lL = leaf_nodes[2 * p];
        const float lR = leaf_nodes[2 * p + 1];
        ws16[i] = make_int4(f, __float_as_int(b),
                            __float_as_int(lL), __float_as_int(lR));
        return;
    }
    p = i - off;
    const int   f0 = nodes_lv[l * PADW + p];
    const float b0 = biases_lv[l * PADW + p];
    const int   fL = nodes_lv[(l + 1) * PADW + 2 * p];
    const int   fR = nodes_lv[(l + 1) * PADW + 2 * p + 1];
    const float bL = biases_lv[(l + 1) * PADW + 2 * p];
    const float bR = biases_lv[(l + 1) * PADW + 2 * p + 1];
    ws16[i] = make_int4(f0 | (fL << 10) | (fR << 20), __float_as_int(b0),
                        __float_as_int(bL), __float_as_int(bR));
}

__global__ __launch_bounds__(THREADS) void gbdt_walk_kernel(
    const float* __restrict__ x,
    const int*   __restrict__ root_nodes,
    const float* __restrict__ root_biases,
    const int4*  __restrict__ ws16,
    float*       __restrict__ out)
{
    __shared__ float xs[ROWS * XSS];        // 131,840 B

    const int tid = threadIdx.x;
    const int b0  = blockIdx.x * ROWS;

    // ---- stage 64 x-rows into LDS (coalesced float4 loads, scalar ds writes) ----
    const float4* __restrict__ xr = (const float4*)(x + (size_t)b0 * FF);
    #pragma unroll
    for (int i = 0; i < (ROWS * FF / 4) / THREADS; ++i) {   // 8 iters
        int fidx = i * THREADS + tid;
        int r = fidx >> 7, c4 = fidx & 127;
        float4 v = xr[fidx];
        float* d = &xs[r * XSS + (c4 << 2)];
        d[0] = v.x; d[1] = v.y; d[2] = v.z; d[3] = v.w;
    }
    __syncthreads();

    const int wv   = tid >> 6;
    const int lane = tid & 63;
    const int tb   = wv * TPW;
    const float* __restrict__ xrow = &xs[lane * XSS];
    float* __restrict__ orow = out + (size_t)(b0 + lane) * TT;

    #pragma unroll
    for (int s = 0; s < TPW / 4; ++s) {     // 8 steps, 4 interleaved chains
        const int t0 = __builtin_amdgcn_readfirstlane(tb + 4 * s);
        int p[4];
        #pragma unroll
        for (int c = 0; c < 4; ++c) {
            const int t = t0 + c;           // wave-uniform -> scalar loads
            p[c] = 2 * t + (xrow[root_nodes[t]] >= root_biases[t] ? 1 : 0);
        }

        // ---- three fused 2-level stages ----
        const int offs[3] = { PT0_OFF, PT1_OFF, PT2_OFF };
        #pragma unroll
        for (int j = 0; j < 3; ++j) {
            int4 r[4];
            #pragma unroll
            for (int c = 0; c < 4; ++c) r[c] = ws16[offs[j] + p[c]];
            #pragma unroll
            for (int c = 0; c < 4; ++c) {
                const int   fp = r[c].x;
                const bool  g0 = xrow[fp & 1023] >= __int_as_float(r[c].y);
                const int   f1 = g0 ? ((fp >> 20) & 1023) : ((fp >> 10) & 1023);
                const float h1 = g0 ? __int_as_float(r[c].w) : __int_as_float(r[c].z);
                const bool  g1 = xrow[f1] >= h1;
                p[c] = 4 * p[c] + 2 * (int)g0 + (int)g1;
            }
        }

        // ---- final stage: level 6 + leaf in one record ----
        int4 r3[4];
        #pragma unroll
        for (int c = 0; c < 4; ++c) r3[c] = ws16[PT3_OFF + p[c]];
        float4 v;
        {
            const bool g = xrow[r3[0].x] >= __int_as_float(r3[0].y);
            v.x = g ? __int_as_float(r3[0].w) : __int_as_float(r3[0].z);
        }
        {
            const bool g = xrow[r3[1].x] >= __int_as_float(r3[1].y);
            v.y = g ? __int_as_float(r3[1].w) : __int_as_float(r3[1].z);
        }
        {
            const bool g = xrow[r3[2].x] >= __int_as_float(r3[2].y);
            v.z = g ? __int_as_float(r3[2].w) : __int_as_float(r3[2].z);
        }
        {
            const bool g = xrow[r3[3].x] >= __int_as_float(r3[3].y);
            v.w = g ? __int_as_float(r3[3].w) : __int_as_float(r3[3].z);
        }
        *(float4*)&orow[t0] = v;
    }
}

// Fallback (ws too small): R5-style direct gathers from the original tables.
__global__ __launch_bounds__(THREADS) void gbdt_walk_fallback(
    const float* __restrict__ x,
    const int*   __restrict__ root_nodes,
    const float* __restrict__ root_biases,
    const int*   __restrict__ nodes_lv,
    const float* __restrict__ biases_lv,
    const float* __restrict__ leaf_nodes,
    float*       __restrict__ out)
{
    __shared__ float xs[ROWS * XSS];
    const int tid = threadIdx.x;
    const int b0  = blockIdx.x * ROWS;
    const float4* __restrict__ xr = (const float4*)(x + (size_t)b0 * FF);
    #pragma unroll
    for (int i = 0; i < (ROWS * FF / 4) / THREADS; ++i) {
        int fidx = i * THREADS + tid;
        int r = fidx >> 7, c4 = fidx & 127;
        float4 v = xr[fidx];
        float* d = &xs[r * XSS + (c4 << 2)];
        d[0] = v.x; d[1] = v.y; d[2] = v.z; d[3] = v.w;
    }
    __syncthreads();
    const int wv   = tid >> 6;
    const int lane = tid & 63;
    const int tb   = wv * TPW;
    const float* __restrict__ xrow = &xs[lane * XSS];
    float* __restrict__ orow = out + (size_t)(b0 + lane) * TT;
    #pragma unroll
    for (int s = 0; s < TPW; ++s) {
        const int t = tb + s;
        int p = 2 * t + (xrow[root_nodes[t]] >= root_biases[t] ? 1 : 0);
        #pragma unroll
        for (int l = 0; l < 7; ++l) {
            const int   f = nodes_lv[l * PADW + p];
            const float h = biases_lv[l * PADW + p];
            p = 2 * p + (xrow[f] >= h ? 1 : 0);
        }
        orow[t] = leaf_nodes[p];
    }
}

extern "C" void kernel_launch(void* const* d_in, const int* in_sizes, int n_in,
                              void* d_out, int out_size, void* d_ws, size_t ws_size,
                              hipStream_t stream) {
    const float* x            = (const float*)d_in[0];
    const int*   root_nodes   = (const int*)  d_in[1];
    const float* root_biases  = (const float*)d_in[2];
    const int*   nodes_lv     = (const int*)  d_in[4];
    const float* biases_lv    = (const float*)d_in[5];
    const float* leaf_nodes   = (const float*)d_in[6];
    float*       out          = (float*)d_out;

    dim3 grid(BB / ROWS);   // 512 blocks
    dim3 block(THREADS);

    if (ws_size >= (size_t)N_REC * 16) {
        int4* ws16 = (int4*)d_ws;
        build_tables_kernel<<<(N_REC + 255) / 256, 256, 0, stream>>>(
            nodes_lv, biases_lv, leaf_nodes, ws16);
        gbdt_walk_kernel<<<grid, block, 0, stream>>>(
            x, root_nodes, root_biases, ws16, out);
    } else {
        gbdt_walk_fallback<<<grid, block, 0, stream>>>(
            x, root_nodes, root_biases, nodes_lv, biases_lv, leaf_nodes, out);
    }
}